// Round 7
// baseline (873.589 us; speedup 1.0000x reference)
//
#include <hip/hip_runtime.h>

// Autoregressive FFNN. out[b,0]=0; t=1..511: mi=[x[b,t,:],pred]; h=relu(mi@W1+b1); pred=h@W2+b2.
// B=4096,T=512,F=63. 256 WGs x 1024 thr (16 waves, 4 waves/SIMD), 16 batch rows/WG, persistent.
// R6: W=16 hidden-split (4 N-tiles/wave) for 2x occupancy vs R5; reader-side pred gather is
// 1 ds_read_b128 (lane c reads wave c's partial) + 4-stage shfl_xor butterfly over c.
// Kept from R5: raw s_barrier + lgkmcnt-only drain (global prefetch stays in flight),
// LDS bf16 x-staging (1 elem/thread), b1 folded into MFMA k=63 slot, VALU pred feedback.

#define TT 512
#define FF 63
#define HID 1024

typedef __attribute__((ext_vector_type(8))) short short8;
typedef __attribute__((ext_vector_type(4))) float f32x4;

__device__ __forceinline__ unsigned short f2bf(float f) {
  union { float f; unsigned u; } v; v.f = f;
  unsigned r = v.u + 0x7FFFu + ((v.u >> 16) & 1u);  // RNE
  return (unsigned short)(r >> 16);
}

// LDS-visibility barrier WITHOUT the vmcnt(0) drain of __syncthreads.
__device__ __forceinline__ void lds_barrier() {
  asm volatile("s_waitcnt lgkmcnt(0)" ::: "memory");
  __builtin_amdgcn_s_barrier();
  asm volatile("" ::: "memory");
}

// butterfly stage: v[q] += shfl_xor(v[q], M) (proven R1/R4/R5)
template<int M>
__device__ __forceinline__ f32x4 sflxadd4(f32x4 v) {
  f32x4 r;
#pragma unroll
  for (int q = 0; q < 4; ++q) r[q] = v[q] + __shfl_xor(v[q], M, 64);
  return r;
}

__global__ __launch_bounds__(1024, 4)
void ffnn_ar_kernel(const float* __restrict__ x,
                    const float* __restrict__ W1,
                    const float* __restrict__ b1,
                    const float* __restrict__ W2,
                    const float* __restrict__ b2p,
                    float* __restrict__ out) {
  __shared__ __align__(16) unsigned short lds_A[2][16][72];  // bf16 x-tiles (col63 = 1.0)
  __shared__ __align__(16) float lds_part[2][16][20];        // [buf][wave][16 rows + pad]

  const int tid  = threadIdx.x;
  const int lane = tid & 63;
  const int w    = tid >> 6;    // wave 0..15: owns hidden cols [64w, 64w+64)
  const int c    = lane & 15;   // A row (batch row) / hidden sub-col
  const int g    = lane >> 4;   // k-group / acc row-block
  const int br   = blockIdx.x * 16;

  // ---- weights (one-time): 4 N-tiles per wave; b1 in k=63 slot ----
  short8 bfr[4][2];
  float  w63f[4], w2f[4];
#pragma unroll
  for (int i = 0; i < 4; ++i) {
    const int n = (w * 4 + i) * 16 + c;
#pragma unroll
    for (int ks = 0; ks < 2; ++ks) {
      short8 f;
#pragma unroll
      for (int j = 0; j < 8; ++j) {
        const int k = ks * 32 + g * 8 + j;
        const float val = (k == 63) ? b1[n] : W1[k * HID + n];
        f[j] = (short)f2bf(val);
      }
      bfr[i][ks] = f;
    }
    w63f[i] = W1[63 * HID + n];
    w2f[i]  = W2[n];
  }
  const float b2 = b2p[0];

  // ---- x staging: wave w stages batch row w; elem = lane (0..62) ----
  const long rowbase = (long)(br + w) * (TT * FF);
  const bool st = (lane < 63);

  // prologue: stage x_1 -> buf1; col63 = 1.0; part buf0: zeros with [0][row] = -b2
  if (st) lds_A[1][w][lane] = f2bf(x[rowbase + FF + lane]);
  if (tid < 16) { lds_A[0][tid][63] = 0x3F80; lds_A[1][tid][63] = 0x3F80; }
  if (tid < 640) reinterpret_cast<float*>(lds_part)[tid] = 0.f;
  if (tid < 16) lds_part[0][0][tid] = -b2;  // sum over waves + b2 = 0 => pred_0 = 0

  // 2 prefetch sets: S0 = x_2, S1 = x_3
  float s0 = st ? x[rowbase + 2 * FF + lane] : 0.f;
  float s1 = st ? x[rowbase + 3 * FF + lane] : 0.f;

  lds_barrier();

#define STEP(T, CUR, S)                                                            \
  {                                                                                \
    /* A-frags for x_T */                                                          \
    const short8 a0 = *reinterpret_cast<const short8*>(&lds_A[CUR][c][g * 8]);     \
    const short8 a1 = *reinterpret_cast<const short8*>(&lds_A[CUR][c][32 + g * 8]);\
    /* pred_{T-1}: lane c reads wave-c's partial, butterfly over c sums 16 waves */\
    f32x4 pr = *reinterpret_cast<const f32x4*>(&lds_part[(CUR) ^ 1][c][g * 4]);    \
    pr = sflxadd4<1>(pr); pr = sflxadd4<2>(pr);                                    \
    pr = sflxadd4<4>(pr); pr = sflxadd4<8>(pr);                                    \
    const float p0 = pr[0] + b2, p1 = pr[1] + b2;                                  \
    const float p2 = pr[2] + b2, p3 = pr[3] + b2;                                  \
    f32x4 acc[4];                                                                  \
    _Pragma("unroll") for (int i = 0; i < 4; ++i) {                                \
      f32x4 z4 = {0.f, 0.f, 0.f, 0.f};                                             \
      z4 = __builtin_amdgcn_mfma_f32_16x16x32_bf16(a0, bfr[i][0], z4, 0, 0, 0);    \
      z4 = __builtin_amdgcn_mfma_f32_16x16x32_bf16(a1, bfr[i][1], z4, 0, 0, 0);    \
      acc[i] = z4;                                                                 \
    }                                                                              \
    /* store pred_{T-1}: wave0, c==0 lanes own rows g*4+q */                       \
    if (w == 0 && c == 0) {                                                        \
      out[(long)(br + g * 4 + 0) * TT + ((T) - 1)] = p0;                           \
      out[(long)(br + g * 4 + 1) * TT + ((T) - 1)] = p1;                           \
      out[(long)(br + g * 4 + 2) * TT + ((T) - 1)] = p2;                           \
      out[(long)(br + g * 4 + 3) * TT + ((T) - 1)] = p3;                           \
    }                                                                              \
    /* stage x_{T+1} from prefetch reg (loaded 2 steps ago) */                     \
    if (st) lds_A[(CUR) ^ 1][w][lane] = f2bf(S);                                   \
    /* reload reg <- x_{T+3} (stays in flight across raw barriers) */              \
    {                                                                              \
      const int tp = ((T) + 3 < TT) ? (T) + 3 : TT - 1;                            \
      if (st) S = x[rowbase + (long)tp * FF + lane];                               \
    }                                                                              \
    /* layer2: z = acc(+b1 in MFMA) + pred*w63 ; h=relu ; part += h*w2 */          \
    f32x4 part = {0.f, 0.f, 0.f, 0.f};                                             \
    _Pragma("unroll") for (int i = 0; i < 4; ++i) {                                \
      part[0] = fmaf(fmaxf(fmaf(p0, w63f[i], acc[i][0]), 0.f), w2f[i], part[0]);   \
      part[1] = fmaf(fmaxf(fmaf(p1, w63f[i], acc[i][1]), 0.f), w2f[i], part[1]);   \
      part[2] = fmaf(fmaxf(fmaf(p2, w63f[i], acc[i][2]), 0.f), w2f[i], part[2]);   \
      part[3] = fmaf(fmaxf(fmaf(p3, w63f[i], acc[i][3]), 0.f), w2f[i], part[3]);   \
    }                                                                              \
    part = sflxadd4<1>(part); part = sflxadd4<2>(part);                            \
    part = sflxadd4<4>(part); part = sflxadd4<8>(part);                            \
    if (c == 0) *reinterpret_cast<f32x4*>(&lds_part[CUR][w][g * 4]) = part;        \
    lds_barrier();                                                                 \
  }

#pragma unroll 1
  for (int t = 1; t + 1 < TT; t += 2) {
    STEP(t, 1, s0)
    STEP(t + 1, 0, s1)
  }
  STEP(TT - 1, 1, s0)  // t = 511 (odd, CUR=1, writes part[1])

  // final: gather pred_511 from part[1] and store out[., 511]
  {
    f32x4 pr = *reinterpret_cast<const f32x4*>(&lds_part[1][c][g * 4]);
    pr = sflxadd4<1>(pr); pr = sflxadd4<2>(pr);
    pr = sflxadd4<4>(pr); pr = sflxadd4<8>(pr);
    if (w == 0 && c == 0) {
#pragma unroll
      for (int q = 0; q < 4; ++q)
        out[(long)(br + g * 4 + q) * TT + (TT - 1)] = pr[q] + b2;
    }
  }
#undef STEP
}

extern "C" void kernel_launch(void* const* d_in, const int* in_sizes, int n_in,
                              void* d_out, int out_size, void* d_ws, size_t ws_size,
                              hipStream_t stream) {
  const float* x   = (const float*)d_in[0];
  // d_in[1] = labels (unused by the reference forward pass)
  const float* W1  = (const float*)d_in[2];
  const float* b1  = (const float*)d_in[3];
  const float* W2  = (const float*)d_in[4];
  const float* b2  = (const float*)d_in[5];
  float* out = (float*)d_out;

  ffnn_ar_kernel<<<256, 1024, 0, stream>>>(x, W1, b1, W2, b2, out);
}